// Round 13
// baseline (284.888 us; speedup 1.0000x reference)
//
#include <hip/hip_runtime.h>

// NeighbourCovariance: per vertex v, gather K=40 neighbors, weight features by
// exp(-10*distsq), compute per-feature weighted mean (C=3) and covariance (3x3).
// Output layout per vertex: [cov (F*9)] ++ [means (F*3)] = 384 floats.
//
// R15 = R14 resubmitted verbatim (R14's bench was an infra failure: container
// died twice; the experiment never ran). Rationale unchanged:
// R8 (best known: bench 242.0, main ~86 us) + spill-free software-pipelined
// gather. Ledger: VALU cut (R5/R12) flat; LDS cut (R13) slower; fetch cut
// (R11) slower; the residual ~29 us above VALU-busy in R8 is exposed gather
// latency. R6 attacked it but spilled (runtime-indexed feats[40]). This
// version pipelines with NAMED registers only (struct of scalars):
//   5 chunks of 8: issue chunk c+1's 8 fp16 gathers BEFORE consuming chunk c.
//   -> >=8 loads always in flight during the 8x13-VALU consume phase.
// Also: joff LDS reads as 2x ds_read_b128 int4 per chunk (was 8x b32).
// __launch_bounds__(256,8) pins VGPR<=64 so occupancy stays 8 blocks/CU
// (32 waves) with LDS 18944 B.
//
//  Pass 0:  cvt features f32 -> fp16 [V][32] in d_ws (~5 us).
//  Phase 1: 320 (v,k) pairs; NT stream loads of nidx/distsq, one exp per pair,
//           coord gather; stage (w,x,y,z) + j*F offset in LDS.
//  Phase 2: lane=(v, f 0..31); pipelined chunks: {load8 next | consume8 cur}.
//  Phase 3: LDS-staged output (R4 mapping, 0 conflicts) -> coalesced 16B NT
//           writeback.
// f32 fallback (R4 structure) if ws too small.

constexpr int K = 40;
constexpr int C = 3;
constexpr int F = 32;
constexpr float EPS = 1e-3f;
constexpr float DIST_SCALE = 10.0f;
constexpr int OUT_PER_V = F * C * C + F * C; // 384
constexpr int VPB = 8;                        // vertices per 256-thread block
constexpr int PAIRS = VPB * K;                // 320
constexpr int OUT_DW = VPB * OUT_PER_V;       // 3072 dwords staged per block
constexpr int OUT_F4 = OUT_DW / 4;            // 768 float4 per block

typedef float    floatx4 __attribute__((ext_vector_type(4)));  // nt-store ok
typedef float    f32x8   __attribute__((ext_vector_type(8)));
typedef _Float16 f16x8   __attribute__((ext_vector_type(8)));

// ---- Pass 0: features f32 -> fp16 (12.8 MB -> 6.4 MB), 8 elems/thread ----
__global__ __launch_bounds__(256) void cvt_kernel(
    const float* __restrict__ in, _Float16* __restrict__ out16, int n8)
{
    const int i = blockIdx.x * 256 + threadIdx.x;
    if (i < n8) {
        const f32x8 v = __builtin_nontemporal_load((const f32x8*)in + i);
        const f16x8 o = __builtin_convertvector(v, f16x8);
        *((f16x8*)out16 + i) = o;   // cached store: re-read by main kernel
    }
}

// ---- Pipeline helpers: named scalars only (rule #20: no runtime indexing) ----
struct F8 { _Float16 a, b, c, d, e, f, g, h; };     // one gather chunk
struct Acc {
    float ws, m0, m1, m2, s00, s01, s02, s11, s12, s22;
};

__device__ __forceinline__ F8 load8(const _Float16* __restrict__ ft,
                                    const int* __restrict__ jp, int kb, int f)
{
    const int4 j0 = *(const int4*)(jp + kb);      // ds_read_b128 broadcast
    const int4 j1 = *(const int4*)(jp + kb + 4);  // ds_read_b128 broadcast
    F8 r;
    r.a = ft[j0.x + f]; r.b = ft[j0.y + f];       // 8 independent 2B gathers
    r.c = ft[j0.z + f]; r.d = ft[j0.w + f];       // (issued before consume of
    r.e = ft[j1.x + f]; r.f = ft[j1.y + f];       //  the previous chunk)
    r.g = ft[j1.z + f]; r.h = ft[j1.w + f];
    return r;
}

__device__ __forceinline__ void body(const float4 q, _Float16 fh, Acc& A)
{
    const float feat = (float)fh;
    const float fw = q.x * feat;         // w==0 encodes invalid neighbor
    const float x = q.y, y = q.z, z = q.w;
    const float fx = fw * x, fy = fw * y, fz = fw * z;
    A.ws  += fw;
    A.m0  += fx;      A.m1  += fy;      A.m2  += fz;
    A.s00 += fx * x;  A.s01 += fx * y;  A.s02 += fx * z;
    A.s11 += fy * y;  A.s12 += fy * z;  A.s22 += fz * z;
}

__device__ __forceinline__ void consume8(const float4* __restrict__ wp, int kb,
                                         const F8& g, Acc& A)
{
    body(wp[kb + 0], g.a, A); body(wp[kb + 1], g.b, A);
    body(wp[kb + 2], g.c, A); body(wp[kb + 3], g.d, A);
    body(wp[kb + 4], g.e, A); body(wp[kb + 5], g.f, A);
    body(wp[kb + 6], g.g, A); body(wp[kb + 7], g.h, A);
}

// ---- Main kernel: fp16 gather, 2-stage pipelined ----
__global__ __launch_bounds__(256, 8) void neighcov_f16(
    const float* __restrict__ coords,      // V x 3
    const float* __restrict__ distsq,      // V x K
    const _Float16* __restrict__ features, // V x F fp16
    const int*   __restrict__ nidx,        // V x K
    float* __restrict__ out,               // V x 384
    int V)
{
    __shared__ float4  s_wxyz[PAIRS];   // (w, x, y, z) per (v,k)       5120 B
    __shared__ int     s_joff[PAIRS];   // j*F element offset           1280 B
    __shared__ floatx4 s_out4[OUT_F4];  // staged output               12288 B

    const int tid   = threadIdx.x;
    const int vbase = blockIdx.x * VPB;
    const long long total_pairs = (long long)V * K;

    // ---- Phase 1: stage weights/coords, 320 pairs ----
    #pragma unroll
    for (int p = tid; p < PAIRS; p += 256) {
        const long long gp = (long long)vbase * K + p;
        int idx = -1;
        float d = 0.f;
        if (gp < total_pairs) {
            idx = __builtin_nontemporal_load(nidx + gp);    // coalesced, single-use
            d   = __builtin_nontemporal_load(distsq + gp);  // coalesced, single-use
        }
        const bool valid = (idx >= 0);
        const int j = valid ? idx : 0;
        const float w = valid ? __expf(-DIST_SCALE * d) : 0.f;  // w==0 = invalid
        const float x = coords[(size_t)j * 3 + 0];
        const float y = coords[(size_t)j * 3 + 1];
        const float z = coords[(size_t)j * 3 + 2];
        s_wxyz[p] = make_float4(w, x, y, z);
        s_joff[p] = j * F;
    }
    __syncthreads();

    // ---- Phase 2: pipelined gather+accumulate, lane = (vertex, feature) ----
    const int f    = tid & (F - 1);
    const int vloc = tid >> 5;
    const float4* wp = &s_wxyz[vloc * K];
    const int*    jp = &s_joff[vloc * K];

    Acc A = {0.f, 0.f, 0.f, 0.f, 0.f, 0.f, 0.f, 0.f, 0.f, 0.f};

    F8 u = load8(features, jp, 0, f);             // prologue: chunk 0 in flight
    F8 v;
    v = load8(features, jp,  8, f); consume8(wp,  0, u, A);
    u = load8(features, jp, 16, f); consume8(wp,  8, v, A);
    v = load8(features, jp, 24, f); consume8(wp, 16, u, A);
    u = load8(features, jp, 32, f); consume8(wp, 24, v, A);
                                    consume8(wp, 32, u, A);

    const float inv = 1.f / (A.ws + EPS);
    const float mu0 = A.m0 * inv, mu1 = A.m1 * inv, mu2 = A.m2 * inv;
    const float c00 = A.s00 * inv - mu0 * mu0;
    const float c01 = A.s01 * inv - mu0 * mu1;
    const float c02 = A.s02 * inv - mu0 * mu2;
    const float c11 = A.s11 * inv - mu1 * mu1;
    const float c12 = A.s12 * inv - mu1 * mu2;
    const float c22 = A.s22 * inv - mu2 * mu2;

    // Stage results in LDS. R4 mapping: f*9 mod 32 bijective -> 0 conflicts.
    float* s_out = (float*)s_out4;
    float* so = s_out + vloc * OUT_PER_V + f * 9;
    so[0] = c00; so[1] = c01; so[2] = c02;
    so[3] = c01; so[4] = c11; so[5] = c12;
    so[6] = c02; so[7] = c12; so[8] = c22;
    float* sm = s_out + vloc * OUT_PER_V + F * 9 + f * 3;
    sm[0] = mu0; sm[1] = mu1; sm[2] = mu2;

    __syncthreads();

    // ---- Phase 3: coalesced non-temporal 16B writeback ----
    const int rem_v  = V - vbase;  // >= 1
    const int lim_f4 = (rem_v >= VPB) ? OUT_F4 : rem_v * (OUT_PER_V / 4);
    floatx4* o4 = (floatx4*)(out + (size_t)vbase * OUT_PER_V);
    #pragma unroll
    for (int g = tid; g < OUT_F4; g += 256) {
        if (g < lim_f4) {
            __builtin_nontemporal_store(s_out4[g], o4 + g);  // contiguous b128
        }
    }
}

// ---- Fallback: R4 structure, f32 features (95 us known-good) ----
__global__ __launch_bounds__(256) void neighcov_f32(
    const float* __restrict__ coords, const float* __restrict__ distsq,
    const float* __restrict__ features, const int* __restrict__ nidx,
    float* __restrict__ out, int V)
{
    __shared__ float4  s_wxyz[PAIRS];
    __shared__ int     s_joff[PAIRS];
    __shared__ floatx4 s_out4[OUT_F4];

    const int tid   = threadIdx.x;
    const int vbase = blockIdx.x * VPB;
    const long long total_pairs = (long long)V * K;

    #pragma unroll
    for (int p = tid; p < PAIRS; p += 256) {
        const long long gp = (long long)vbase * K + p;
        int idx = -1; float d = 0.f;
        if (gp < total_pairs) {
            idx = __builtin_nontemporal_load(nidx + gp);
            d   = __builtin_nontemporal_load(distsq + gp);
        }
        const bool valid = (idx >= 0);
        const int j = valid ? idx : 0;
        const float w = valid ? __expf(-DIST_SCALE * d) : 0.f;
        s_wxyz[p] = make_float4(w, coords[(size_t)j * 3 + 0],
                                coords[(size_t)j * 3 + 1], coords[(size_t)j * 3 + 2]);
        s_joff[p] = j * F;
    }
    __syncthreads();

    const int f = tid & (F - 1), vloc = tid >> 5;
    const float4* wp = &s_wxyz[vloc * K];
    const int*    jp = &s_joff[vloc * K];

    float wsum = 0.f, m0 = 0.f, m1 = 0.f, m2 = 0.f;
    float s00 = 0.f, s01 = 0.f, s02 = 0.f, s11 = 0.f, s12 = 0.f, s22 = 0.f;
    #pragma unroll 8
    for (int k = 0; k < K; ++k) {
        const float4 q = wp[k];
        const float feat = features[jp[k] + f];
        const float fw = q.x * feat;
        const float x = q.y, y = q.z, z = q.w;
        const float fx = fw * x, fy = fw * y, fz = fw * z;
        wsum += fw; m0 += fx; m1 += fy; m2 += fz;
        s00 += fx * x; s01 += fx * y; s02 += fx * z;
        s11 += fy * y; s12 += fy * z; s22 += fz * z;
    }
    const float inv = 1.f / (wsum + EPS);
    const float mu0 = m0 * inv, mu1 = m1 * inv, mu2 = m2 * inv;
    float* s_out = (float*)s_out4;
    float* so = s_out + vloc * OUT_PER_V + f * 9;
    so[0] = s00 * inv - mu0 * mu0; so[1] = s01 * inv - mu0 * mu1;
    so[2] = s02 * inv - mu0 * mu2; so[3] = so[1];
    so[4] = s11 * inv - mu1 * mu1; so[5] = s12 * inv - mu1 * mu2;
    so[6] = so[2]; so[7] = so[5]; so[8] = s22 * inv - mu2 * mu2;
    float* sm = s_out + vloc * OUT_PER_V + F * 9 + f * 3;
    sm[0] = mu0; sm[1] = mu1; sm[2] = mu2;
    __syncthreads();

    const int rem_v = V - vbase;
    const int lim_f4 = (rem_v >= VPB) ? OUT_F4 : rem_v * (OUT_PER_V / 4);
    floatx4* o4 = (floatx4*)(out + (size_t)vbase * OUT_PER_V);
    #pragma unroll
    for (int g = tid; g < OUT_F4; g += 256)
        if (g < lim_f4) __builtin_nontemporal_store(s_out4[g], o4 + g);
}

extern "C" void kernel_launch(void* const* d_in, const int* in_sizes, int n_in,
                              void* d_out, int out_size, void* d_ws, size_t ws_size,
                              hipStream_t stream) {
    const float* coords   = (const float*)d_in[0];
    const float* distsq   = (const float*)d_in[1];
    const float* features = (const float*)d_in[2];
    const int*   nidx     = (const int*)d_in[3];
    float* out = (float*)d_out;

    const int V = in_sizes[0] / C;            // coordinates is V x 3
    const int blocks = (V + VPB - 1) / VPB;   // 8 vertices per 256-thread block

    const size_t need = (size_t)V * F * sizeof(_Float16);
    const int nelem = V * F;
    if (ws_size >= need && (nelem & 7) == 0) {
        _Float16* feat16 = (_Float16*)d_ws;
        const int n8 = nelem / 8;
        cvt_kernel<<<(n8 + 255) / 256, 256, 0, stream>>>(features, feat16, n8);
        neighcov_f16<<<blocks, 256, 0, stream>>>(
            coords, distsq, feat16, nidx, out, V);
    } else {
        neighcov_f32<<<blocks, 256, 0, stream>>>(
            coords, distsq, features, nidx, out, V);
    }
}